// Round 9
// baseline (130.789 us; speedup 1.0000x reference)
//
#include <hip/hip_runtime.h>
#include <hip/hip_bf16.h>

typedef unsigned short u16;
typedef unsigned int u32;
typedef __attribute__((ext_vector_type(8))) short short8;   // 8 bf16 fragment (4 VGPRs)
typedef __attribute__((ext_vector_type(8))) u16 ushort8;
typedef __attribute__((ext_vector_type(4))) float f32x4;

#define B_SZ 4096
#define D_SZ 512
#define NCLS 64
#define NT   64                      // 4096/64 tiles per dimension
#define NBLK (NT * (NT + 1) / 2)     // 2080 lower-triangular tiles (2080 % 8 == 0)

// ---------------- helpers ----------------

__device__ __forceinline__ u16 f2bf(float x) {
    union { float f; u32 u; } a; a.f = x;
    u32 r = a.u + 0x7fffu + ((a.u >> 16) & 1u);   // round-to-nearest-even
    return (u16)(r >> 16);
}

// ---------------- kernel 1: fp32->bf16 copy, row sq-norms, accumulator init ----------------

__global__ __launch_bounds__(256) void prep_kernel(
    const float* __restrict__ in, u16* __restrict__ bfout,
    float* __restrict__ sq, float* __restrict__ ap_sum, u32* __restrict__ an_min,
    int* __restrict__ done)
{
    if (blockIdx.x == 0 && threadIdx.x == 0) *done = 0;
    const int wave = threadIdx.x >> 6, l = threadIdx.x & 63;
    const int row = blockIdx.x * 4 + wave;
    const float* p = in + (size_t)row * D_SZ + l * 8;
    float4 v0 = *(const float4*)p;
    float4 v1 = *(const float4*)(p + 4);
    float s = v0.x*v0.x + v0.y*v0.y + v0.z*v0.z + v0.w*v0.w
            + v1.x*v1.x + v1.y*v1.y + v1.z*v1.z + v1.w*v1.w;
    ushort8 o;
    o[0]=f2bf(v0.x); o[1]=f2bf(v0.y); o[2]=f2bf(v0.z); o[3]=f2bf(v0.w);
    o[4]=f2bf(v1.x); o[5]=f2bf(v1.y); o[6]=f2bf(v1.z); o[7]=f2bf(v1.w);
    *(ushort8*)(bfout + (size_t)row * D_SZ + l * 8) = o;
    #pragma unroll
    for (int off = 1; off < 64; off <<= 1) s += __shfl_xor(s, off);
    if (l == 0) {
        sq[row] = s;
        ap_sum[row] = 0.0f;
        an_min[row] = 0x7f800000u;   // +inf bits
    }
}

// ---------------- kernel 2: single-wave 64x64 tiles, register-direct, no barriers ----------------
// 2080 independent 1-wave blocks. Each lane loads its MFMA fragments DIRECTLY
// from global (16 B short8; K-step pairs share 128 B lines -> full line use).
// No LDS staging, no __syncthreads in the K-loop: 8+ decoupled waves/CU drift
// in phase and hide each other's latency. Last block (done-counter) finalizes.

__global__ __launch_bounds__(64) void tile_kernel(
    const u16* __restrict__ bfin, const int* __restrict__ lab,
    const float* __restrict__ sq, float* __restrict__ ap_sum, u32* __restrict__ an_min,
    int* __restrict__ done, float* __restrict__ out)
{
    __shared__ float sqA[64], sqB[64];
    __shared__ int labA[64], labB[64];
    __shared__ int cnt[NCLS];

    const int lane = threadIdx.x;
    const int c = lane & 15, g = lane >> 4;

    // XCD-chunked bijective swizzle: 2080 % 8 == 0 -> each XCD gets 260 consecutive tiles
    int bid = blockIdx.x;
    bid = (bid & 7) * (NBLK / 8) + (bid >> 3);

    // triangular decode: bid -> (tm, tn), tm >= tn
    int tm = (int)((__builtin_sqrtf(8.0f * (float)bid + 1.0f) - 1.0f) * 0.5f);
    while ((tm + 1) * (tm + 2) / 2 <= bid) ++tm;
    while (tm * (tm + 1) / 2 > bid) --tm;
    const int tn = bid - tm * (tm + 1) / 2;
    const bool diag = (tm == tn);

    const int rowBase = tm * 64;
    const int colBase = tn * 64;

    sqA[lane] = sq[rowBase + lane]; labA[lane] = lab[rowBase + lane];
    sqB[lane] = sq[colBase + lane]; labB[lane] = lab[colBase + lane];
    __syncthreads();   // single wave: cheap; orders LDS fill before epilogue reads

    f32x4 acc[4][4];
    #pragma unroll
    for (int i = 0; i < 4; ++i)
        #pragma unroll
        for (int j = 0; j < 4; ++j)
            acc[i][j] = (f32x4){0.f, 0.f, 0.f, 0.f};

    // fragment base: lane (c,g) covers row (16*mi + c), k-chunk g of each K-step
    const u16* pa = bfin + (size_t)(rowBase + c) * D_SZ + g * 8;
    const u16* pb = bfin + (size_t)(colBase + c) * D_SZ + g * 8;

    #pragma unroll 2
    for (int kk = 0; kk < D_SZ / 32; ++kk) {
        short8 a[4], b[4];
        #pragma unroll
        for (int mi = 0; mi < 4; ++mi)
            a[mi] = *(const short8*)(pa + (size_t)mi * 16 * D_SZ + kk * 32);
        #pragma unroll
        for (int ni = 0; ni < 4; ++ni)
            b[ni] = *(const short8*)(pb + (size_t)ni * 16 * D_SZ + kk * 32);
        #pragma unroll
        for (int mi = 0; mi < 4; ++mi)
            #pragma unroll
            for (int ni = 0; ni < 4; ++ni)
                acc[mi][ni] = __builtin_amdgcn_mfma_f32_16x16x32_bf16(a[mi], b[ni], acc[mi][ni], 0, 0, 0);
    }

    // Epilogue. C/D layout: col = lane&15, row = (lane>>4)*4 + reg (per 16x16 block).
    float sc[4], mc[4];
    #pragma unroll
    for (int ni = 0; ni < 4; ++ni) { sc[ni] = 0.0f; mc[ni] = __builtin_inff(); }

    #pragma unroll
    for (int mi = 0; mi < 4; ++mi) {
        #pragma unroll
        for (int r = 0; r < 4; ++r) {
            const int lrow = mi * 16 + g * 4 + r;
            const int i = rowBase + lrow;
            const int li = labA[lrow];
            const float sqi = sqA[lrow];
            float s = 0.0f;
            float mn = __builtin_inff();
            #pragma unroll
            for (int ni = 0; ni < 4; ++ni) {
                const int lcol = ni * 16 + c;
                float d2 = sqi + sqB[lcol] - 2.0f * acc[mi][ni][r];
                d2 = fmaxf(d2, 0.0f);
                float dist = (d2 > 1e-12f) ? __builtin_sqrtf(d2) : 0.0f;
                if (diag && lrow == lcol) dist = 0.0f;   // self distance exactly 0
                if (li == labB[lcol]) { s += dist; sc[ni] += dist; }
                else                  { mn = fminf(mn, dist); mc[ni] = fminf(mc[ni], dist); }
            }
            // row-side: reduce across the 16 c-lanes of this g-group
            #pragma unroll
            for (int off = 1; off < 16; off <<= 1) {
                s += __shfl_xor(s, off);
                mn = fminf(mn, __shfl_xor(mn, off));
            }
            if (c == 0) {
                atomicAdd(&ap_sum[i], s);
                atomicMin(&an_min[i], __float_as_uint(mn));   // dist >= 0: uint order == float order
            }
        }
    }

    if (!diag) {
        // column-side: reduce across the 4 g-groups, then atomic per column
        #pragma unroll
        for (int ni = 0; ni < 4; ++ni) {
            float s = sc[ni], mn = mc[ni];
            s += __shfl_xor(s, 16); s += __shfl_xor(s, 32);
            mn = fminf(mn, __shfl_xor(mn, 16)); mn = fminf(mn, __shfl_xor(mn, 32));
            if (lane < 16) {
                const int j = colBase + ni * 16 + c;
                atomicAdd(&ap_sum[j], s);
                atomicMin(&an_min[j], __float_as_uint(mn));
            }
        }
    }

    // ---- done-counter handshake (1 wave: vmcnt is per-wave, fence covers all lanes) ----
    __threadfence();   // completes + orders this wave's atomics before the increment
    int isLast = 0;
    if (lane == 0) {
        int old = atomicAdd(done, 1);
        isLast = (old == NBLK - 1) ? 1 : 0;
    }
    isLast = __shfl(isLast, 0);
    if (!isLast) return;

    // ---- finalize (last block; all 2080 blocks' atomics complete & coherent) ----
    cnt[lane] = 0;   // NCLS == 64 == wave width
    __syncthreads();
    for (int i = lane; i < B_SZ; i += 64) atomicAdd(&cnt[lab[i]], 1);
    __syncthreads();
    float v = 0.0f;
    #pragma unroll 8
    for (int i = lane; i < B_SZ; i += 64) {
        // atomic RMW reads: coherent at the memory side (plain loads could hit stale lines)
        float apv = atomicAdd(&ap_sum[i], 0.0f);
        u32 mnb = atomicMin(&an_min[i], 0x7f800000u);   // min(x, +inf) == x, returns old
        v += fmaxf(apv / (float)cnt[lab[i]] - __uint_as_float(mnb) + 1.0f, 0.0f);  // MARGIN = 1
    }
    #pragma unroll
    for (int off = 1; off < 64; off <<= 1) v += __shfl_xor(v, off);
    if (lane == 0) out[0] = v;
}

// ---------------- launch ----------------

extern "C" void kernel_launch(void* const* d_in, const int* in_sizes, int n_in,
                              void* d_out, int out_size, void* d_ws, size_t ws_size,
                              hipStream_t stream) {
    const float* inputs = (const float*)d_in[0];
    const int* labels = (const int*)d_in[1];
    float* out = (float*)d_out;

    // workspace layout (~4.3 MB)
    char* ws = (char*)d_ws;
    float* ap_sum = (float*)ws;            // 4096 floats
    u32* an_min = (u32*)(ws + 16384);      // 4096 u32
    float* sq = (float*)(ws + 32768);      // 4096 floats
    int* done = (int*)(ws + 49152);        // 1 int
    u16* bfin = (u16*)(ws + 65536);        // 4096*512 bf16 = 4 MB

    prep_kernel<<<dim3(B_SZ / 4), dim3(256), 0, stream>>>(inputs, bfin, sq, ap_sum, an_min, done);
    tile_kernel<<<dim3(NBLK), dim3(64), 0, stream>>>(bfin, labels, sq, ap_sum, an_min, done, out);
}

// Round 10
// 50.623 us; speedup vs baseline: 2.5836x; 2.5836x over previous
//
#include <hip/hip_runtime.h>
#include <hip/hip_bf16.h>

typedef unsigned short u16;
typedef unsigned int u32;
typedef __attribute__((ext_vector_type(8))) short short8;   // 8 bf16 fragment (4 VGPRs)
typedef __attribute__((ext_vector_type(8))) u16 ushort8;
typedef __attribute__((ext_vector_type(4))) float f32x4;

#define B_SZ 4096
#define D_SZ 512
#define NCLS 64
#define BK   32
#define NKK  (D_SZ / BK)             // 16 K-steps
#define NT   32                      // 4096/128 tiles per dimension
#define NBLK (NT * (NT + 1) / 2)     // 528 lower-triangular tiles (528 % 8 == 0)
#define TILE_ELEMS (128 * BK)        // 4096 u16 = 8 KB per buffer

// ---------------- helpers ----------------

__device__ __forceinline__ u16 f2bf(float x) {
    union { float f; u32 u; } a; a.f = x;
    u32 r = a.u + 0x7fffu + ((a.u >> 16) & 1u);   // round-to-nearest-even
    return (u16)(r >> 16);
}

__device__ __forceinline__ void gload16(const void* g, void* l) {
    // async global -> LDS, 16 bytes per lane; LDS dest = wave-uniform base + lane*16
    __builtin_amdgcn_global_load_lds(
        (const __attribute__((address_space(1))) u32*)g,
        (__attribute__((address_space(3))) u32*)l,
        16, 0, 0);
}

// Stage a 128x32 bf16 tile into LDS (linear dest), XOR-pre-swizzling the GLOBAL
// source chunk (4 chunks/row): reduces the 64B-row-stride ds_read conflict from
// 8-way to ~4-way (R4-measured 1.08M vs R1's 2.1M). chunk' = chunk ^ (row & 3).
__device__ __forceinline__ void stage_tile32(const u16* __restrict__ gsrc, u16* dst, int t) {
    #pragma unroll
    for (int q = 0; q < 2; ++q) {
        const int s = t + q * 256;
        const int r = s >> 2;                       // row 0..127
        const int col = ((s & 3) ^ (r & 3)) << 3;   // swizzled 8-elem chunk within row
        gload16(gsrc + (size_t)r * D_SZ + col, dst + s * 8);
    }
}

// ---------------- kernel 1: fp32->bf16 copy, row sq-norms, accumulator init ----------------

__global__ __launch_bounds__(256) void prep_kernel(
    const float* __restrict__ in, u16* __restrict__ bfout,
    float* __restrict__ sq, float* __restrict__ ap_sum, u32* __restrict__ an_min,
    int* __restrict__ done)
{
    if (blockIdx.x == 0 && threadIdx.x == 0) *done = 0;
    const int wave = threadIdx.x >> 6, l = threadIdx.x & 63;
    const int row = blockIdx.x * 4 + wave;
    const float* p = in + (size_t)row * D_SZ + l * 8;
    float4 v0 = *(const float4*)p;
    float4 v1 = *(const float4*)(p + 4);
    float s = v0.x*v0.x + v0.y*v0.y + v0.z*v0.z + v0.w*v0.w
            + v1.x*v1.x + v1.y*v1.y + v1.z*v1.z + v1.w*v1.w;
    ushort8 o;
    o[0]=f2bf(v0.x); o[1]=f2bf(v0.y); o[2]=f2bf(v0.z); o[3]=f2bf(v0.w);
    o[4]=f2bf(v1.x); o[5]=f2bf(v1.y); o[6]=f2bf(v1.z); o[7]=f2bf(v1.w);
    *(ushort8*)(bfout + (size_t)row * D_SZ + l * 8) = o;
    #pragma unroll
    for (int off = 1; off < 64; off <<= 1) s += __shfl_xor(s, off);
    if (l == 0) {
        sq[row] = s;
        ap_sum[row] = 0.0f;
        an_min[row] = 0x7f800000u;   // +inf bits
    }
}

// ---------------- kernel 2: fused Gram + distance + reductions + finalize ----------------
// R2-proven tile structure: 528 triangular 128x128 tiles, BK=32 SINGLE buffer,
// two __syncthreads per K-step (empirically the per-CU throughput champion:
// 0.082 tiles/us/CU — dbuf/counted-vmcnt/1-wave variants all <= this).
// 18.5 KB LDS -> 8 blocks/CU cap. Fused finalize via R8-proven done-counter.

__global__ __launch_bounds__(256) void tile_kernel(
    const u16* __restrict__ bfin, const int* __restrict__ lab,
    const float* __restrict__ sq, float* __restrict__ ap_sum, u32* __restrict__ an_min,
    int* __restrict__ done, float* __restrict__ out)
{
    __shared__ u16 As[TILE_ELEMS];
    __shared__ u16 Bs[TILE_ELEMS];
    __shared__ float sqA[128], sqB[128];
    __shared__ int labA[128], labB[128];
    __shared__ int isLast;
    __shared__ float wsum[4];

    const int t = threadIdx.x;

    // XCD-chunked bijective swizzle: 528 % 8 == 0 -> each XCD gets 66 consecutive tiles
    int bid = blockIdx.x;
    bid = (bid & 7) * (NBLK / 8) + (bid >> 3);

    // triangular decode: bid -> (tm, tn), tm >= tn
    int tm = (int)((__builtin_sqrtf(8.0f * (float)bid + 1.0f) - 1.0f) * 0.5f);
    while ((tm + 1) * (tm + 2) / 2 <= bid) ++tm;
    while (tm * (tm + 1) / 2 > bid) --tm;
    const int tn = bid - tm * (tm + 1) / 2;
    const bool diag = (tm == tn);

    const int rowBase = tm * 128;
    const int colBase = tn * 128;

    if (t < 128) { labA[t] = lab[rowBase + t]; sqA[t] = sq[rowBase + t]; }
    else { int u = t - 128; labB[u] = lab[colBase + u]; sqB[u] = sq[colBase + u]; }

    const int wave = t >> 6, lane = t & 63;
    const int wr = wave >> 1, wc = wave & 1;
    const int g = lane >> 4, c = lane & 15;

    f32x4 acc[4][4];
    #pragma unroll
    for (int i = 0; i < 4; ++i)
        #pragma unroll
        for (int j = 0; j < 4; ++j)
            acc[i][j] = (f32x4){0.f, 0.f, 0.f, 0.f};

    const u16* gA = bfin + (size_t)rowBase * D_SZ;
    const u16* gB = bfin + (size_t)colBase * D_SZ;

    // swizzled read offset: LDS[row][chunk] = global[row][chunk ^ (row&3)]; row%4 == c%4
    const int sw = (g ^ (c & 3)) << 3;

    #pragma unroll 1
    for (int kk = 0; kk < NKK; ++kk) {
        stage_tile32(gA + kk * BK, As, t);
        if (!diag) stage_tile32(gB + kk * BK, Bs, t);
        __syncthreads();   // vmcnt(0) drain + barrier: tile ready for all waves

        const u16* abuf = As;
        const u16* bbuf = diag ? As : Bs;

        short8 a[4], b[4];
        #pragma unroll
        for (int mi = 0; mi < 4; ++mi)
            a[mi] = *(const short8*)&abuf[(wr * 64 + mi * 16 + c) * BK + sw];
        #pragma unroll
        for (int ni = 0; ni < 4; ++ni)
            b[ni] = *(const short8*)&bbuf[(wc * 64 + ni * 16 + c) * BK + sw];

        #pragma unroll
        for (int mi = 0; mi < 4; ++mi)
            #pragma unroll
            for (int ni = 0; ni < 4; ++ni)
                acc[mi][ni] = __builtin_amdgcn_mfma_f32_16x16x32_bf16(a[mi], b[ni], acc[mi][ni], 0, 0, 0);

        __syncthreads();   // readers done before next-step overwrite
    }

    // Epilogue. C/D layout: col = lane&15, row = (lane>>4)*4 + reg.
    float sc[4], mc[4];
    #pragma unroll
    for (int ni = 0; ni < 4; ++ni) { sc[ni] = 0.0f; mc[ni] = __builtin_inff(); }

    #pragma unroll
    for (int mi = 0; mi < 4; ++mi) {
        #pragma unroll
        for (int r = 0; r < 4; ++r) {
            const int lrow = wr * 64 + mi * 16 + g * 4 + r;
            const int i = rowBase + lrow;
            const int li = labA[lrow];
            const float sqi = sqA[lrow];
            float s = 0.0f;
            float mn = __builtin_inff();
            #pragma unroll
            for (int ni = 0; ni < 4; ++ni) {
                const int lcol = wc * 64 + ni * 16 + c;
                float d2 = sqi + sqB[lcol] - 2.0f * acc[mi][ni][r];
                d2 = fmaxf(d2, 0.0f);
                float dist = (d2 > 1e-12f) ? __builtin_sqrtf(d2) : 0.0f;
                if (diag && lrow == lcol) dist = 0.0f;   // self distance exactly 0
                if (li == labB[lcol]) { s += dist; sc[ni] += dist; }
                else                  { mn = fminf(mn, dist); mc[ni] = fminf(mc[ni], dist); }
            }
            // row-side: reduce across the 16 c-lanes of this g-group
            #pragma unroll
            for (int off = 1; off < 16; off <<= 1) {
                s += __shfl_xor(s, off);
                mn = fminf(mn, __shfl_xor(mn, off));
            }
            if (c == 0) {
                atomicAdd(&ap_sum[i], s);
                atomicMin(&an_min[i], __float_as_uint(mn));   // dist >= 0: uint order == float order
            }
        }
    }

    if (!diag) {
        // column-side: reduce across the 4 g-groups, then atomic per column
        #pragma unroll
        for (int ni = 0; ni < 4; ++ni) {
            float s = sc[ni], mn = mc[ni];
            s += __shfl_xor(s, 16); s += __shfl_xor(s, 32);
            mn = fminf(mn, __shfl_xor(mn, 16)); mn = fminf(mn, __shfl_xor(mn, 32));
            if (lane < 16) {
                const int j = colBase + wc * 64 + ni * 16 + c;
                atomicAdd(&ap_sum[j], s);
                atomicMin(&an_min[j], __float_as_uint(mn));
            }
        }
    }

    // ---- done-counter handshake (R8-proven): last block finalizes ----
    __syncthreads();   // all waves' atomics issued & drained (vmcnt(0) per wave)
    if (t == 0) {
        __threadfence();
        int old = atomicAdd(done, 1);
        isLast = (old == NBLK - 1) ? 1 : 0;
    }
    __syncthreads();
    if (!isLast) return;

    // ---- finalize (last block; all 528 blocks' atomics complete & coherent) ----
    int* cnt = labA;   // reuse shared [64]
    if (t < NCLS) cnt[t] = 0;
    __syncthreads();
    for (int i = t; i < B_SZ; i += 256) atomicAdd(&cnt[lab[i]], 1);
    __syncthreads();
    float v = 0.0f;
    for (int i = t; i < B_SZ; i += 256) {
        // atomic RMW reads: coherent at the memory side (plain loads could hit stale lines)
        float apv = atomicAdd(&ap_sum[i], 0.0f);
        u32 mnb = atomicMin(&an_min[i], 0x7f800000u);   // min(x, +inf) == x, returns old
        v += fmaxf(apv / (float)cnt[lab[i]] - __uint_as_float(mnb) + 1.0f, 0.0f);  // MARGIN = 1
    }
    #pragma unroll
    for (int off = 1; off < 64; off <<= 1) v += __shfl_xor(v, off);
    if ((t & 63) == 0) wsum[t >> 6] = v;
    __syncthreads();
    if (t == 0) out[0] = wsum[0] + wsum[1] + wsum[2] + wsum[3];
}

// ---------------- launch ----------------

extern "C" void kernel_launch(void* const* d_in, const int* in_sizes, int n_in,
                              void* d_out, int out_size, void* d_ws, size_t ws_size,
                              hipStream_t stream) {
    const float* inputs = (const float*)d_in[0];
    const int* labels = (const int*)d_in[1];
    float* out = (float*)d_out;

    // workspace layout (~4.3 MB)
    char* ws = (char*)d_ws;
    float* ap_sum = (float*)ws;            // 4096 floats
    u32* an_min = (u32*)(ws + 16384);      // 4096 u32
    float* sq = (float*)(ws + 32768);      // 4096 floats
    int* done = (int*)(ws + 49152);        // 1 int
    u16* bfin = (u16*)(ws + 65536);        // 4096*512 bf16 = 4 MB

    prep_kernel<<<dim3(B_SZ / 4), dim3(256), 0, stream>>>(inputs, bfin, sq, ap_sum, an_min, done);
    tile_kernel<<<dim3(NBLK), dim3(256), 0, stream>>>(bfin, labels, sq, ap_sum, an_min, done, out);
}